// Round 10
// baseline (684.419 us; speedup 1.0000x reference)
//
#include <hip/hip_runtime.h>
#include <math.h>

typedef float f32x4 __attribute__((ext_vector_type(4)));
typedef short bf16x8 __attribute__((ext_vector_type(8)));
typedef unsigned short u16;

typedef const __attribute__((address_space(1))) unsigned int ga_u32;
typedef __attribute__((address_space(3))) unsigned int ls_u32;

__device__ __forceinline__ void gl16(const void* g, void* l) {
    __builtin_amdgcn_global_load_lds((ga_u32*)g, (ls_u32*)l, 16, 0, 0);
}

__device__ __forceinline__ u16 f2bf(float f) {
    union { float f; unsigned u; } v; v.f = f;
    return (u16)((v.u + 0x7FFFu + ((v.u >> 16) & 1u)) >> 16);
}
__device__ __forceinline__ float bf2f(u16 h) {
    union { unsigned u; float f; } v; v.u = ((unsigned)h) << 16;
    return v.f;
}
__device__ __forceinline__ float splusf(float x) {
    return fmaxf(x, 0.f) + __logf(1.f + __expf(-fabsf(x)));
}

#define MID_ACT_P 264

// ---------------------------------------------------------------------------
// setup: build masked bf16 weights (+padded Wo), fused biases, eta->AXE cols
// ---------------------------------------------------------------------------
__global__ __launch_bounds__(256) void setup_w(
    const float* __restrict__ Win, const float* __restrict__ bin,
    const float* __restrict__ Wctx, const float* __restrict__ bctx,
    const float* __restrict__ Wblk, const float* __restrict__ Wout,
    const float* __restrict__ bout, const float* __restrict__ eta,
    u16* __restrict__ W1, float* __restrict__ B1, u16* __restrict__ WB,
    u16* __restrict__ WO, float* __restrict__ BO, u16* __restrict__ AXE)
{
    const long N1 = 8L * 256 * 96;
    const long N2 = 8L * 256;
    const long N3 = 8L * 4 * 256 * 256;
    const long N4 = 8L * 3072 * 256;
    const long N5 = 8L * 3072;
    const long N6 = 8192L * 32;
    const long tot = N1 + N2 + N3 + N4 + N5 + N6;
    for (long i = (long)blockIdx.x * blockDim.x + threadIdx.x; i < tot;
         i += (long)gridDim.x * blockDim.x) {
        long t = i;
        if (t < N1) {
            long l = t / (256 * 96); long r = t % (256 * 96);
            int j = (int)(r / 96), c = (int)(r % 96);
            float v;
            if (c < 64) v = Win[(l * 256 + j) * 64 + c] * (((j % 63) >= c) ? 1.f : 0.f);
            else        v = Wctx[(l * 256 + j) * 32 + (c - 64)];
            W1[i] = f2bf(v);
        } else if ((t -= N1) < N2) {
            B1[t] = bin[t] + bctx[t];
        } else if ((t -= N2) < N3) {
            int rr = (int)((t / 256) % 256);
            int c = (int)(t % 256);
            float v = Wblk[t] * (((rr % 63) >= (c % 63)) ? 1.f : 0.f);
            WB[t] = f2bf(v);
        } else if ((t -= N3) < N4) {
            long l = t / (3072 * 256); long r = t % (3072 * 256);
            int op = (int)(r / 256), j = (int)(r % 256);
            int fd = op / 48, mm = op % 48;
            float v = 0.f;
            if (mm < 47 && fd > (j % 63))
                v = Wout[(l * 3008 + (long)fd * 47 + mm) * 256 + j];
            WO[t] = f2bf(v);
        } else if ((t -= N4) < N5) {
            long l = t / 3072; int op = (int)(t % 3072);
            int fd = op / 48, mm = op % 48;
            BO[t] = (mm < 47) ? bout[l * 3008 + (long)fd * 47 + mm] : 0.f;
        } else {
            t -= N5;
            long b = t / 32; int p = (int)(t % 32);
            AXE[b * 96 + 64 + p] = f2bf(eta[t]);
        }
    }
}

// ---------------------------------------------------------------------------
// data stats
// ---------------------------------------------------------------------------
__global__ __launch_bounds__(128) void dstat(const float* __restrict__ D,
                                             float* __restrict__ DM)
{
    int j = threadIdx.x;
    float s = 0.f, q = 0.f;
    if (j < 65) {
        for (int m = 0; m < 256; ++m) {
            float v = D[m * 65 + j];
            s += v; q += v * v;
        }
        DM[j] = s * (1.f / 256.f);
    }
    __shared__ float red[128];
    red[j] = q; __syncthreads();
    for (int st = 64; st > 0; st >>= 1) {
        if (j < st) red[j] += red[j + st];
        __syncthreads();
    }
    if (j == 0) DM[65] = red[0] * (1.f / 256.f);
}

// ---------------------------------------------------------------------------
// prep0: flip z -> XF (f32) + AXE cols 0..63 (bf16)
// ---------------------------------------------------------------------------
__global__ __launch_bounds__(256) void prep0(
    const float* __restrict__ z, float* __restrict__ XF, u16* __restrict__ AXE)
{
    size_t gt = (size_t)blockIdx.x * 256 + threadIdx.x;
    size_t b = gt >> 6; int f = (int)(gt & 63);
    float v = z[b * 64 + (63 - f)];
    XF[gt] = v;
    AXE[b * 96 + f] = f2bf(v);
}

// ---------------------------------------------------------------------------
// mid GEMM stage: 16 rows x 256 out-channels, K = NK*32 (R9-proven).
// ---------------------------------------------------------------------------
template<int NK>
__device__ __forceinline__ void mid_stage(
    const u16* __restrict__ Wsrc, int wpitch,
    u16* __restrict__ Wq0, u16* __restrict__ Wq1,
    const u16* __restrict__ act,
    int tid, int fr, int kg, int ch0, f32x4 (&acc)[2])
{
    const int swr = tid >> 1;
    const int swp = (tid & 1) << 4;
    const u16* gW = Wsrc + (size_t)swr * wpitch + swp;

    *(int4*)&Wq0[swr * 40 + swp]     = *(const int4*)(gW);
    *(int4*)&Wq0[swr * 40 + swp + 8] = *(const int4*)(gW + 8);

#pragma unroll
    for (int ks = 0; ks < NK; ++ks) {
        const u16* cbuf = (ks & 1) ? Wq1 : Wq0;
        u16*       nbuf = (ks & 1) ? Wq0 : Wq1;
        int4 p0, p1;
        const bool more = (ks + 1 < NK);
        if (more) {
            p0 = *(const int4*)(gW + (ks + 1) * 32);
            p1 = *(const int4*)(gW + (ks + 1) * 32 + 8);
        }
        __syncthreads();
        bf16x8 wf0 = *(const bf16x8*)&cbuf[(ch0 + fr) * 40 + kg * 8];
        bf16x8 wf1 = *(const bf16x8*)&cbuf[(ch0 + 16 + fr) * 40 + kg * 8];
        bf16x8 af0 = *(const bf16x8*)&act[fr * MID_ACT_P + ks * 32 + kg * 8];
        acc[0] = __builtin_amdgcn_mfma_f32_16x16x32_bf16(wf0, af0, acc[0], 0, 0, 0);
        acc[1] = __builtin_amdgcn_mfma_f32_16x16x32_bf16(wf1, af0, acc[1], 0, 0, 0);
        if (more) {
            *(int4*)&nbuf[swr * 40 + swp]     = p0;
            *(int4*)&nbuf[swr * 40 + swp + 8] = p1;
        }
    }
    __syncthreads();
}

// fused_mid: all 5 mid GEMMs. 512 blocks x 16 batch rows, 512 thr.
// Final epilogue writes HB XOR-swizzled (16B-chunk ^ (row&7)) so the out
// kernel's linear gl16 staging + XOR read is bank-conflict-free (R8-proven).
__global__ __launch_bounds__(512) void fused_mid(
    const u16* __restrict__ AXE, const u16* __restrict__ W1l,
    const float* __restrict__ B1l, const u16* __restrict__ WBl,
    const float* __restrict__ bbl, u16* __restrict__ HB)
{
    __shared__ u16 Wq0[256 * 40];
    __shared__ u16 Wq1[256 * 40];
    __shared__ u16 act[16 * MID_ACT_P];
    const int tid = threadIdx.x;
    const int lane = tid & 63;
    const int wv = tid >> 6;
    const int fr = lane & 15, kg = lane >> 4;
    const int b0 = blockIdx.x * 16;
    const int ch0 = wv * 32;
    const int swzW = (fr & 7) << 3;

    if (tid < 192) {
        int row = tid / 12, part = tid - row * 12;
        *(int4*)&act[row * MID_ACT_P + part * 8] =
            *(const int4*)&AXE[(size_t)(b0 + row) * 96 + part * 8];
    }

    f32x4 H[2], T[2];

    auto zeroT = [&]() {
        T[0] = (f32x4){0.f, 0.f, 0.f, 0.f};
        T[1] = (f32x4){0.f, 0.f, 0.f, 0.f};
    };
    auto epi = [&](const float* bias, int mode) {
#pragma unroll
        for (int m = 0; m < 2; ++m) {
            const int cb = ch0 + m * 16 + kg * 4;
            const float4 bs = *(const float4*)&bias[cb];
            f32x4 v = T[m];
            v[0] += bs.x; v[1] += bs.y; v[2] += bs.z; v[3] += bs.w;
            if (mode == 0) H[m] = v;
            if (mode == 2 || mode == 3) {
                H[m][0] += v[0]; H[m][1] += v[1];
                H[m][2] += v[2]; H[m][3] += v[3];
                v = H[m];
            }
            short4 q;
            if (mode != 3) {
                q.x = (short)f2bf(fmaxf(v[0], 0.f));
                q.y = (short)f2bf(fmaxf(v[1], 0.f));
                q.z = (short)f2bf(fmaxf(v[2], 0.f));
                q.w = (short)f2bf(fmaxf(v[3], 0.f));
                *(short4*)&act[fr * MID_ACT_P + cb] = q;
            } else {
                q.x = (short)f2bf(v[0]); q.y = (short)f2bf(v[1]);
                q.z = (short)f2bf(v[2]); q.w = (short)f2bf(v[3]);
                *(short4*)&HB[(size_t)(b0 + fr) * 256 + (cb ^ swzW)] = q;
            }
        }
    };

    zeroT();
    mid_stage<3>(W1l, 96, Wq0, Wq1, act, tid, fr, kg, ch0, T);
    epi(B1l, 0);
    zeroT();
    mid_stage<8>(WBl, 256, Wq0, Wq1, act, tid, fr, kg, ch0, T);
    epi(bbl, 1);
    zeroT();
    mid_stage<8>(WBl + 65536, 256, Wq0, Wq1, act, tid, fr, kg, ch0, T);
    epi(bbl + 256, 2);
    zeroT();
    mid_stage<8>(WBl + 2 * 65536, 256, Wq0, Wq1, act, tid, fr, kg, ch0, T);
    epi(bbl + 2 * 256, 1);
    zeroT();
    mid_stage<8>(WBl + 3 * 65536, 256, Wq0, Wq1, act, tid, fr, kg, ch0, T);
    epi(bbl + 3 * 256, 3);
}

// ---------------------------------------------------------------------------
// Out-GEMM (64x96 tile, K=256) + fused RQS spline.
// A (HB, swizzled in global) staged ONCE via gl16 into 32KB linear LDS;
// frag reads apply the XOR -> conflict-free. B (Wo) global->reg, 1-deep
// prefetch. K-loop has zero barriers, zero LDS writes. 4 blocks/CU.
// ---------------------------------------------------------------------------
__global__ __launch_bounds__(256) void gemm_out_spline(
    const u16* __restrict__ A, const u16* __restrict__ Wo,
    const float* __restrict__ bo, const float* __restrict__ XF,
    float* __restrict__ Xn, float* __restrict__ XFnext, u16* __restrict__ AXE,
    float* __restrict__ LDP, int first)
{
    __shared__ u16 SM[16384];       // 32 KB: A tile [64][256]; dump alias
    __shared__ float ldpart[2][64];
    const int tid = threadIdx.x;
    const int lane = tid & 63, wv = tid >> 6;
    const int wm = wv >> 1, wn = wv & 1;
    const int fr = lane & 15, kg = lane >> 4;
    const int m0 = blockIdx.x * 64, n0 = blockIdx.y * 96;
    const int swz = (fr & 7) << 3;

    // stage A (rows m0..m0+63, already swizzled) linearly: 8 x 4KB
    const u16* gA = A + (size_t)m0 * 256;
#pragma unroll
    for (int i = 0; i < 8; ++i)
        gl16(gA + i * 2048 + tid * 8, &SM[i * 2048 + tid * 8]);

    const u16* gB0 = Wo + (size_t)(n0 + wn * 48 +  0 + fr) * 256 + kg * 8;
    const u16* gB1 = Wo + (size_t)(n0 + wn * 48 + 16 + fr) * 256 + kg * 8;
    const u16* gB2 = Wo + (size_t)(n0 + wn * 48 + 32 + fr) * 256 + kg * 8;

    f32x4 acc[2][3];
#pragma unroll
    for (int m = 0; m < 2; ++m)
#pragma unroll
        for (int n = 0; n < 3; ++n) acc[m][n] = (f32x4){0.f, 0.f, 0.f, 0.f};

    bf16x8 nb0 = *(const bf16x8*)gB0;
    bf16x8 nb1 = *(const bf16x8*)gB1;
    bf16x8 nb2 = *(const bf16x8*)gB2;

    __syncthreads();   // A tile resident (drains gl16)

#pragma unroll
    for (int ks = 0; ks < 8; ++ks) {
        bf16x8 bf0 = nb0, bf1 = nb1, bf2 = nb2;
        if (ks < 7) {
            nb0 = *(const bf16x8*)(gB0 + (ks + 1) * 32);
            nb1 = *(const bf16x8*)(gB1 + (ks + 1) * 32);
            nb2 = *(const bf16x8*)(gB2 + (ks + 1) * 32);
        }
        const int co = (ks * 32 + kg * 8) ^ swz;
        bf16x8 af0 = *(const bf16x8*)&SM[(wm * 32 +  0 + fr) * 256 + co];
        bf16x8 af1 = *(const bf16x8*)&SM[(wm * 32 + 16 + fr) * 256 + co];
        acc[0][0] = __builtin_amdgcn_mfma_f32_16x16x32_bf16(bf0, af0, acc[0][0], 0, 0, 0);
        acc[0][1] = __builtin_amdgcn_mfma_f32_16x16x32_bf16(bf1, af0, acc[0][1], 0, 0, 0);
        acc[0][2] = __builtin_amdgcn_mfma_f32_16x16x32_bf16(bf2, af0, acc[0][2], 0, 0, 0);
        acc[1][0] = __builtin_amdgcn_mfma_f32_16x16x32_bf16(bf0, af1, acc[1][0], 0, 0, 0);
        acc[1][1] = __builtin_amdgcn_mfma_f32_16x16x32_bf16(bf1, af1, acc[1][1], 0, 0, 0);
        acc[1][2] = __builtin_amdgcn_mfma_f32_16x16x32_bf16(bf2, af1, acc[1][2], 0, 0, 0);
    }
    __syncthreads();   // all A reads done before dump aliases SM

    // dump acc(+bias) as bf16, pitch 104 u16 (64 rows x 96 cols)
#pragma unroll
    for (int m = 0; m < 2; ++m) {
        const int row = wm * 32 + m * 16 + fr;
#pragma unroll
        for (int n = 0; n < 3; ++n) {
            const int c0 = wn * 48 + n * 16 + kg * 4;
            const float4 bs = *(const float4*)&bo[n0 + c0];
            short4 q;
            q.x = (short)f2bf(acc[m][n][0] + bs.x);
            q.y = (short)f2bf(acc[m][n][1] + bs.y);
            q.z = (short)f2bf(acc[m][n][2] + bs.z);
            q.w = (short)f2bf(acc[m][n][3] + bs.w);
            *(short4*)&SM[row * 104 + c0] = q;
        }
    }
    __syncthreads();

    // ---- spline: 128 splines (64 rows x 2 feats) x 2 threads (w/h split) --
    {
        const int sp = tid >> 1, fi = tid & 1;
        const int r = sp & 63, ff = sp >> 6;
        const int b = m0 + r;
        const int fg = blockIdx.y * 2 + ff;
        const u16* o_ = &SM[r * 104 + ff * 48];

        float xin = XF[(size_t)b * 64 + fg];
        bool inside = (xin >= -10.f) && (xin <= 10.f);
        float xs = fminf(fmaxf(xin, -10.f), 10.f);

        float e[16];
        {
            bf16x8 a  = *(const bf16x8*)(o_ + fi * 16);
            bf16x8 b2 = *(const bf16x8*)(o_ + fi * 16 + 8);
#pragma unroll
            for (int i = 0; i < 8; ++i) {
                e[i]     = bf2f((u16)a[i])  * 0.0625f;
                e[8 + i] = bf2f((u16)b2[i]) * 0.0625f;
            }
        }
        float mx = e[0];
#pragma unroll
        for (int i = 1; i < 16; ++i) mx = fmaxf(mx, e[i]);
        float s = 0.f;
#pragma unroll
        for (int i = 0; i < 16; ++i) { e[i] = __expf(e[i] - mx); s += e[i]; }
        const float kk = 20.f * (1.f - 1.6e-7f) / s;

        int selk = 0;
        float icw = -10.f, iw = 1.f, ich = -10.f, ih = 1.f;
        if (fi == 0) {
            float ck = -10.f;
#pragma unroll
            for (int k = 0; k < 16; ++k) {
                float c1 = (k == 15) ? 10.f : ck + (2e-7f + kk * e[k]);
                if (xs >= ck) { selk = k; icw = ck; iw = c1 - ck; }
                ck = c1;
            }
        }
        selk = __shfl(selk, lane & ~1);
        if (fi == 1) {
            float ck = -10.f;
#pragma unroll
            for (int k = 0; k < 16; ++k) {
                float c1 = (k == 15) ? 10.f : ck + (2e-7f + kk * e[k]);
                if (k == selk) { ich = ck; ih = c1 - ck; }
                ck = c1;
            }
        }
        ich = __shfl(ich, lane | 1);
        ih  = __shfl(ih,  lane | 1);
        if (fi == 0) {
            float udl = (selk >= 1)  ? bf2f(o_[32 + selk - 1]) : 0.f;
            float udr = (selk <= 14) ? bf2f(o_[32 + selk])     : 0.f;
            float d0 = (selk == 0)  ? 1.f : 1e-8f + splusf(udl);
            float d1 = (selk == 15) ? 1.f : 1e-8f + splusf(udr);
            float delta = ih / iw;
            float t = (xs - icw) / iw;
            float tt = t * (1.f - t);
            float denom = delta + (d0 + d1 - 2.f * delta) * tt;
            float y = ich + ih * (delta * t * t + d0 * tt) / denom;
            float omt = 1.f - t;
            float dnum = delta * delta * (d1 * t * t + 2.f * delta * tt + d0 * omt * omt);
            float ldv = __logf(dnum) - 2.f * __logf(denom);
            if (!inside) { y = xin; ldv = 0.f; }

            Xn[(size_t)b * 64 + fg] = y;
            XFnext[(size_t)b * 64 + (63 - fg)] = y;
            AXE[(size_t)b * 96 + (63 - fg)] = f2bf(y);
            ldpart[ff][r] = ldv;
        }
    }
    __syncthreads();
    if (tid < 64) {
        float v = ldpart[0][tid] + ldpart[1][tid];
        size_t o = (size_t)(m0 + tid) * 32 + blockIdx.y;
        LDP[o] = first ? v : (LDP[o] + v);
    }
}

// ---------------------------------------------------------------------------
// finals: stick-breaking + per-sample objective, then reduction
// ---------------------------------------------------------------------------
__global__ __launch_bounds__(256) void final1(
    const float* __restrict__ X, const float* __restrict__ z,
    const float* __restrict__ LDP, const float* __restrict__ DM,
    float* __restrict__ PART)
{
    int tid = threadIdx.x;
    int b = blockIdx.x * 256 + tid;
    float ldt = 0.f;
    for (int g = 0; g < 32; ++g) ldt += LDP[(size_t)b * 32 + g];
    float pre = 0.f, lvs = 0.f, wls = 0.f, lp = 0.f, tdm = 0.f, tsq = 0.f;
    const float LCLIP = -23.02585093f;
    for (int i = 0; i < 64; ++i) {
        float xi = X[(size_t)b * 64 + i];
        float lv = -splusf(-xi), l1 = -splusf(xi);
        float lt = lv + pre;
        float th = __expf(lt);
        lp += fmaxf(lt, LCLIP);
        tdm += th * DM[i]; tsq += th * th;
        lvs += lv; wls += (float)(64 - i) * l1;
        pre += l1;
    }
    float th = __expf(pre);
    lp += fmaxf(pre, LCLIP); tdm += th * DM[64]; tsq += th * th;
    float zs = 0.f;
    for (int i = 0; i < 64; ++i) { float zz = z[(size_t)b * 64 + i]; zs += zz * zz; }
    float logqz = -0.5f * zs - 58.812066f;
    float log_q = logqz - (ldt + lvs + wls);
    float log_lik = -0.5f * (DM[65] - 2.f * tdm + tsq);
    float val = log_q - lp - log_lik;

    __shared__ float red[256];
    red[tid] = val; __syncthreads();
    for (int s = 128; s > 0; s >>= 1) {
        if (tid < s) red[tid] += red[tid + s];
        __syncthreads();
    }
    if (tid == 0) PART[blockIdx.x] = red[0];
}

__global__ __launch_bounds__(64) void final2(const float* __restrict__ PART,
                                             float* __restrict__ out)
{
    int tid = threadIdx.x;
    float s = (tid < 32) ? PART[tid] : 0.f;
    for (int o = 16; o > 0; o >>= 1) s += __shfl_down(s, o);
    if (tid == 0) out[0] = s * (1.f / 8192.f);
}

// ---------------------------------------------------------------------------
extern "C" void kernel_launch(void* const* d_in, const int* in_sizes, int n_in,
                              void* d_out, int out_size, void* d_ws, size_t ws_size,
                              hipStream_t stream)
{
    (void)in_sizes; (void)n_in; (void)out_size; (void)ws_size;
    const float* z    = (const float*)d_in[0];
    const float* eta  = (const float*)d_in[1];
    const float* dat  = (const float*)d_in[2];
    const float* Win  = (const float*)d_in[3];
    const float* bin  = (const float*)d_in[4];
    const float* Wctx = (const float*)d_in[5];
    const float* bctx = (const float*)d_in[6];
    const float* Wblk = (const float*)d_in[7];
    const float* bblk = (const float*)d_in[8];
    const float* Wout = (const float*)d_in[9];
    const float* bout = (const float*)d_in[10];
    float* out = (float*)d_out;

    char* w = (char*)d_ws;
    size_t off = 0;
    auto alloc = [&](size_t bytes) {
        void* p = w + off;
        off += (bytes + 255) & ~(size_t)255;
        return p;
    };
    u16*   W1  = (u16*)  alloc(8L * 256 * 96 * 2);
    float* B1  = (float*)alloc(8L * 256 * 4);
    u16*   WB  = (u16*)  alloc(8L * 4 * 256 * 256 * 2);
    u16*   WO  = (u16*)  alloc(8L * 3072 * 256 * 2);
    float* BO  = (float*)alloc(8L * 3072 * 4);
    u16*   AXE = (u16*)  alloc(8192L * 96 * 2);
    float* XFa = (float*)alloc(8192L * 64 * 4);
    float* XFb = (float*)alloc(8192L * 64 * 4);
    float* XC  = (float*)alloc(8192L * 64 * 4);
    u16*   HB  = (u16*)  alloc(8192L * 256 * 2);
    float* LDP = (float*)alloc(8192L * 32 * 4);
    float* DM  = (float*)alloc(66 * 4);
    float* PART= (float*)alloc(64 * 4);

    setup_w<<<dim3(2048), dim3(256), 0, stream>>>(
        Win, bin, Wctx, bctx, Wblk, Wout, bout, eta, W1, B1, WB, WO, BO, AXE);
    dstat<<<dim3(1), dim3(128), 0, stream>>>(dat, DM);
    prep0<<<dim3(2048), dim3(256), 0, stream>>>(z, XFa, AXE);

    for (int l = 0; l < 8; ++l) {
        float* XFin  = (l & 1) ? XFb : XFa;
        float* XFout = (l & 1) ? XFa : XFb;
        fused_mid<<<dim3(512), dim3(512), 0, stream>>>(
            AXE, W1 + (size_t)l * 256 * 96, B1 + l * 256,
            WB + (size_t)l * 4 * 65536, bblk + (size_t)l * 4 * 256, HB);
        gemm_out_spline<<<dim3(128, 32), dim3(256), 0, stream>>>(
            HB, WO + (size_t)l * 3072 * 256, BO + l * 3072, XFin,
            XC, XFout, AXE, LDP, (l == 0) ? 1 : 0);
    }
    final1<<<dim3(32), dim3(256), 0, stream>>>(XC, z, LDP, DM, PART);
    final2<<<dim3(1), dim3(64), 0, stream>>>(PART, out);
}

// Round 11
// 410.357 us; speedup vs baseline: 1.6679x; 1.6679x over previous
//
#include <hip/hip_runtime.h>
#include <math.h>

typedef float f32x4 __attribute__((ext_vector_type(4)));
typedef short bf16x8 __attribute__((ext_vector_type(8)));
typedef unsigned short u16;

typedef const __attribute__((address_space(1))) unsigned int ga_u32;
typedef __attribute__((address_space(3))) unsigned int ls_u32;

__device__ __forceinline__ void gl16(const void* g, void* l) {
    __builtin_amdgcn_global_load_lds((ga_u32*)g, (ls_u32*)l, 16, 0, 0);
}

__device__ __forceinline__ u16 f2bf(float f) {
    union { float f; unsigned u; } v; v.f = f;
    return (u16)((v.u + 0x7FFFu + ((v.u >> 16) & 1u)) >> 16);
}
__device__ __forceinline__ float bf2f(u16 h) {
    union { unsigned u; float f; } v; v.u = ((unsigned)h) << 16;
    return v.f;
}
__device__ __forceinline__ float splusf(float x) {
    return fmaxf(x, 0.f) + __logf(1.f + __expf(-fabsf(x)));
}

#define MID_ACT_P 264

// ---------------------------------------------------------------------------
// setup: build masked bf16 weights in CHUNK-MAJOR SLICE layout =
// [slice(k/32)][chunk(=kg,8cols)][row][8] — the exact LDS image each K-step
// stages, so global_load_lds is a linear copy and ds_read_b128 is
// conflict-free (16 consecutive 16B granules per quarter-wave).
// ---------------------------------------------------------------------------
__global__ __launch_bounds__(256) void setup_w(
    const float* __restrict__ Win, const float* __restrict__ bin,
    const float* __restrict__ Wctx, const float* __restrict__ bctx,
    const float* __restrict__ Wblk, const float* __restrict__ Wout,
    const float* __restrict__ bout, const float* __restrict__ eta,
    u16* __restrict__ W1, float* __restrict__ B1, u16* __restrict__ WB,
    u16* __restrict__ WO, float* __restrict__ BO, u16* __restrict__ AXE)
{
    const long N1 = 8L * 3 * 4 * 256 * 8;        // W1: [l][ks3][chunk][row256][8]
    const long N2 = 8L * 256;
    const long N3 = 8L * 4 * 8 * 4 * 256 * 8;    // WB: [l][bi][ks8][chunk][row256][8]
    const long N4 = 8L * 32 * 8 * 4 * 96 * 8;    // WO: [l][ytile32][ks8][chunk][row96][8]
    const long N5 = 8L * 3072;
    const long N6 = 8192L * 32;
    const long tot = N1 + N2 + N3 + N4 + N5 + N6;
    for (long i = (long)blockIdx.x * blockDim.x + threadIdx.x; i < tot;
         i += (long)gridDim.x * blockDim.x) {
        long t = i;
        if (t < N1) {
            long l = t / 24576; int rem = (int)(t % 24576);
            int ks = rem / 8192, r2 = rem % 8192;
            int chunk = r2 / 2048, r3 = r2 % 2048;
            int row = r3 / 8, off = r3 % 8;
            int c = ks * 32 + chunk * 8 + off;
            float v;
            if (c < 64) v = Win[(l * 256 + row) * 64 + c] * (((row % 63) >= c) ? 1.f : 0.f);
            else        v = Wctx[(l * 256 + row) * 32 + (c - 64)];
            W1[t] = f2bf(v);
        } else if ((t -= N1) < N2) {
            B1[t] = bin[t] + bctx[t];
        } else if ((t -= N2) < N3) {
            long l = t / 262144; int rem = (int)(t % 262144);
            int bi = rem / 65536, r2 = rem % 65536;
            int ks = r2 / 8192, r3 = r2 % 8192;
            int chunk = r3 / 2048, r4 = r3 % 2048;
            int row = r4 / 8, off = r4 % 8;
            int c = ks * 32 + chunk * 8 + off;
            float v = Wblk[(((size_t)l * 4 + bi) * 256 + row) * 256 + c] *
                      (((row % 63) >= (c % 63)) ? 1.f : 0.f);
            WB[t] = f2bf(v);
        } else if ((t -= N3) < N4) {
            long l = t / 786432; int rem = (int)(t % 786432);
            int y = rem / 24576, r2 = rem % 24576;
            int ks = r2 / 3072, r3 = r2 % 3072;
            int chunk = r3 / 768, r4 = r3 % 768;
            int row = r4 / 8, off = r4 % 8;
            int op = y * 96 + row;
            int j = ks * 32 + chunk * 8 + off;
            int fd = op / 48, mm = op % 48;
            float v = 0.f;
            if (mm < 47 && fd > (j % 63))
                v = Wout[((size_t)l * 3008 + fd * 47 + mm) * 256 + j];
            WO[t] = f2bf(v);
        } else if ((t -= N4) < N5) {
            long l = t / 3072; int op = (int)(t % 3072);
            int fd = op / 48, mm = op % 48;
            BO[t] = (mm < 47) ? bout[l * 3008 + (long)fd * 47 + mm] : 0.f;
        } else {
            t -= N5;
            long b = t / 32; int p = (int)(t % 32);
            AXE[b * 96 + 64 + p] = f2bf(eta[t]);
        }
    }
}

// ---------------------------------------------------------------------------
// data stats
// ---------------------------------------------------------------------------
__global__ __launch_bounds__(128) void dstat(const float* __restrict__ D,
                                             float* __restrict__ DM)
{
    int j = threadIdx.x;
    float s = 0.f, q = 0.f;
    if (j < 65) {
        for (int m = 0; m < 256; ++m) {
            float v = D[m * 65 + j];
            s += v; q += v * v;
        }
        DM[j] = s * (1.f / 256.f);
    }
    __shared__ float red[128];
    red[j] = q; __syncthreads();
    for (int st = 64; st > 0; st >>= 1) {
        if (j < st) red[j] += red[j + st];
        __syncthreads();
    }
    if (j == 0) DM[65] = red[0] * (1.f / 256.f);
}

// ---------------------------------------------------------------------------
// prep0: flip z -> XF (f32) + AXE cols 0..63 (bf16)
// ---------------------------------------------------------------------------
__global__ __launch_bounds__(256) void prep0(
    const float* __restrict__ z, float* __restrict__ XF, u16* __restrict__ AXE)
{
    size_t gt = (size_t)blockIdx.x * 256 + threadIdx.x;
    size_t b = gt >> 6; int f = (int)(gt & 63);
    float v = z[b * 64 + (63 - f)];
    XF[gt] = v;
    AXE[b * 96 + f] = f2bf(v);
}

// ---------------------------------------------------------------------------
// mid stage: weights streamed slice-by-slice via gl16 into dbuf'd chunk-major
// LDS (linear copy of pre-tiled source). Conflict-free b128 frag reads.
// ---------------------------------------------------------------------------
template<int NK>
__device__ __forceinline__ void mid_stage(
    const u16* __restrict__ gWs,   // NK slices of 8192 u16, pre-tiled
    u16* __restrict__ Wq,          // dbuf 2 x 8192 u16
    const u16* __restrict__ act,
    int tid, int fr, int kg, int ch0, f32x4 (&acc)[2])
{
    gl16(gWs + tid * 8,         Wq + tid * 8);
    gl16(gWs + (512 + tid) * 8, Wq + (512 + tid) * 8);

#pragma unroll
    for (int ks = 0; ks < NK; ++ks) {
        __syncthreads();   // drains buf[ks&1] gl16; orders buffer reuse
        if (ks + 1 < NK) {
            const u16* src = gWs + (ks + 1) * 8192;
            u16* nb = Wq + ((ks + 1) & 1) * 8192;
            gl16(src + tid * 8,         nb + tid * 8);
            gl16(src + (512 + tid) * 8, nb + (512 + tid) * 8);
        }
        const u16* cb = Wq + (ks & 1) * 8192;
        bf16x8 wf0 = *(const bf16x8*)&cb[kg * 2048 + (ch0 + fr) * 8];
        bf16x8 wf1 = *(const bf16x8*)&cb[kg * 2048 + (ch0 + 16 + fr) * 8];
        bf16x8 af0 = *(const bf16x8*)&act[fr * MID_ACT_P + ks * 32 + kg * 8];
        acc[0] = __builtin_amdgcn_mfma_f32_16x16x32_bf16(wf0, af0, acc[0], 0, 0, 0);
        acc[1] = __builtin_amdgcn_mfma_f32_16x16x32_bf16(wf1, af0, acc[1], 0, 0, 0);
    }
    __syncthreads();
}

// fused_mid: all 5 mid GEMMs. 512 blocks x 16 batch rows, 512 thr.
// Final epilogue writes HB in the out-kernel's tiled layout
// [xtile128][ks8][chunk][row128][8].
__global__ __launch_bounds__(512) void fused_mid(
    const u16* __restrict__ AXE, const u16* __restrict__ W1l,
    const float* __restrict__ B1l, const u16* __restrict__ WBl,
    const float* __restrict__ bbl, u16* __restrict__ HB)
{
    __shared__ u16 Wq[2 * 8192];          // 32768 B
    __shared__ u16 act[16 * MID_ACT_P];   //  8448 B
    const int tid = threadIdx.x;
    const int lane = tid & 63;
    const int wv = tid >> 6;
    const int fr = lane & 15, kg = lane >> 4;
    const int b0 = blockIdx.x * 16;
    const int ch0 = wv * 32;

    if (tid < 192) {
        int row = tid / 12, part = tid - row * 12;
        *(int4*)&act[row * MID_ACT_P + part * 8] =
            *(const int4*)&AXE[(size_t)(b0 + row) * 96 + part * 8];
    }

    f32x4 H[2], T[2];

    auto zeroT = [&]() {
        T[0] = (f32x4){0.f, 0.f, 0.f, 0.f};
        T[1] = (f32x4){0.f, 0.f, 0.f, 0.f};
    };
    auto epi = [&](const float* bias, int mode) {
#pragma unroll
        for (int m = 0; m < 2; ++m) {
            const int cb = ch0 + m * 16 + kg * 4;
            const float4 bs = *(const float4*)&bias[cb];
            f32x4 v = T[m];
            v[0] += bs.x; v[1] += bs.y; v[2] += bs.z; v[3] += bs.w;
            if (mode == 0) H[m] = v;
            if (mode == 2 || mode == 3) {
                H[m][0] += v[0]; H[m][1] += v[1];
                H[m][2] += v[2]; H[m][3] += v[3];
                v = H[m];
            }
            short4 q;
            if (mode != 3) {
                q.x = (short)f2bf(fmaxf(v[0], 0.f));
                q.y = (short)f2bf(fmaxf(v[1], 0.f));
                q.z = (short)f2bf(fmaxf(v[2], 0.f));
                q.w = (short)f2bf(fmaxf(v[3], 0.f));
                *(short4*)&act[fr * MID_ACT_P + cb] = q;
            } else {
                q.x = (short)f2bf(v[0]); q.y = (short)f2bf(v[1]);
                q.z = (short)f2bf(v[2]); q.w = (short)f2bf(v[3]);
                const int b = b0 + fr;
                const size_t idx =
                    (((size_t)(b >> 7) * 8 + (cb >> 5)) * 4 + ((cb >> 3) & 3)) * 1024
                    + (size_t)(b & 127) * 8 + (cb & 7);
                *(short4*)&HB[idx] = q;
            }
        }
    };

    zeroT();
    mid_stage<3>(W1l, Wq, act, tid, fr, kg, ch0, T);
    epi(B1l, 0);
    zeroT();
    mid_stage<8>(WBl, Wq, act, tid, fr, kg, ch0, T);
    epi(bbl, 1);
    zeroT();
    mid_stage<8>(WBl + 65536, Wq, act, tid, fr, kg, ch0, T);
    epi(bbl + 256, 2);
    zeroT();
    mid_stage<8>(WBl + 2 * 65536, Wq, act, tid, fr, kg, ch0, T);
    epi(bbl + 2 * 256, 1);
    zeroT();
    mid_stage<8>(WBl + 3 * 65536, Wq, act, tid, fr, kg, ch0, T);
    epi(bbl + 3 * 256, 3);
}

// ---------------------------------------------------------------------------
// Out-GEMM (128x96 tile, K=256) + fused RQS spline.
// A (HB) and B (WO) are pre-tiled per (tile, K-slice) in chunk-major order:
// staging is a linear gl16 copy, frag reads are conflict-free. Dbuf, 2
// barriers per K-step, 5 blocks/CU.
// ---------------------------------------------------------------------------
__global__ __launch_bounds__(256) void gemm_out_spline(
    const u16* __restrict__ A, const u16* __restrict__ Wo,
    const float* __restrict__ bo, const float* __restrict__ XF,
    float* __restrict__ Xn, float* __restrict__ XFnext, u16* __restrict__ AXE,
    float* __restrict__ LDP, int first)
{
    __shared__ u16 SM[14336];      // A dbuf 2x4096 | B dbuf 2x3072 (28672 B)
    const int tid = threadIdx.x;
    const int lane = tid & 63, wv = tid >> 6;
    const int wm = wv >> 1, wn = wv & 1;
    const int fr = lane & 15, kg = lane >> 4;
    const int m0 = blockIdx.x * 128, n0 = blockIdx.y * 96;

    u16* Ab = SM;                  // 2 x 4096 u16
    u16* Bb = SM + 8192;           // 2 x 3072 u16

    const u16* gAblk = A  + (size_t)blockIdx.x * 32768;   // 8 slices x 4096
    const u16* gBblk = Wo + (size_t)blockIdx.y * 24576;   // 8 slices x 3072

    f32x4 acc[4][3];
#pragma unroll
    for (int m = 0; m < 4; ++m)
#pragma unroll
        for (int n = 0; n < 3; ++n) acc[m][n] = (f32x4){0.f, 0.f, 0.f, 0.f};

    // prologue: slice 0 -> buf0 (linear copies)
    gl16(gAblk + tid * 8,         Ab + tid * 8);
    gl16(gAblk + (256 + tid) * 8, Ab + (256 + tid) * 8);
    gl16(gBblk + tid * 8,         Bb + tid * 8);
    if (tid < 128)
        gl16(gBblk + (256 + tid) * 8, Bb + (256 + tid) * 8);

#pragma unroll
    for (int ks = 0; ks < 8; ++ks) {
        __syncthreads();   // drains buf[ks&1] gl16; orders buffer reuse
        if (ks < 7) {
            const u16* sa = gAblk + (ks + 1) * 4096;
            const u16* sb = gBblk + (ks + 1) * 3072;
            u16* na = Ab + ((ks + 1) & 1) * 4096;
            u16* nb = Bb + ((ks + 1) & 1) * 3072;
            gl16(sa + tid * 8,         na + tid * 8);
            gl16(sa + (256 + tid) * 8, na + (256 + tid) * 8);
            gl16(sb + tid * 8,         nb + tid * 8);
            if (tid < 128)
                gl16(sb + (256 + tid) * 8, nb + (256 + tid) * 8);
        }
        const u16* cA = Ab + (ks & 1) * 4096;
        const u16* cB = Bb + (ks & 1) * 3072;
        bf16x8 af[4], bf[3];
#pragma unroll
        for (int m = 0; m < 4; ++m)
            af[m] = *(const bf16x8*)&cA[kg * 1024 + (wm * 64 + m * 16 + fr) * 8];
#pragma unroll
        for (int n = 0; n < 3; ++n)
            bf[n] = *(const bf16x8*)&cB[kg * 768 + (wn * 48 + n * 16 + fr) * 8];
#pragma unroll
        for (int m = 0; m < 4; ++m)
#pragma unroll
            for (int n = 0; n < 3; ++n)
                acc[m][n] = __builtin_amdgcn_mfma_f32_16x16x32_bf16(bf[n], af[m], acc[m][n], 0, 0, 0);
    }
    __syncthreads();   // all frag reads done before dump aliases the buffers

    // dump acc(+bias) as bf16, pitch 104 u16, b64 stores (4 cols per lane)
#pragma unroll
    for (int m = 0; m < 4; ++m) {
        const int row = wm * 64 + m * 16 + fr;
#pragma unroll
        for (int n = 0; n < 3; ++n) {
            const int c0 = wn * 48 + n * 16 + kg * 4;
            const float4 bs = *(const float4*)&bo[n0 + c0];
            short4 q;
            q.x = (short)f2bf(acc[m][n][0] + bs.x);
            q.y = (short)f2bf(acc[m][n][1] + bs.y);
            q.z = (short)f2bf(acc[m][n][2] + bs.z);
            q.w = (short)f2bf(acc[m][n][3] + bs.w);
            *(short4*)&SM[row * 104 + c0] = q;
        }
    }
    __syncthreads();

    // ---- RQS spline: one thread per (row, feature); 256 = 128 x 2 ----
    const int r = tid >> 1, fi = tid & 1;
    const int b = m0 + r;
    const int fg = blockIdx.y * 2 + fi;
    const u16* o_ = &SM[r * 104 + fi * 48];
    bf16x8 v0 = *(const bf16x8*)(o_);
    bf16x8 v1 = *(const bf16x8*)(o_ + 8);
    bf16x8 v2 = *(const bf16x8*)(o_ + 16);
    bf16x8 v3 = *(const bf16x8*)(o_ + 24);
    bf16x8 v4 = *(const bf16x8*)(o_ + 32);
    bf16x8 v5 = *(const bf16x8*)(o_ + 40);

    float xin = XF[(size_t)b * 64 + fg];
    bool inside = (xin >= -10.f) && (xin <= 10.f);
    float xs = fminf(fmaxf(xin, -10.f), 10.f);

    float ew[16], eh[16], ud[15];
#pragma unroll
    for (int i = 0; i < 8; ++i) {
        ew[i]     = bf2f((u16)v0[i]) * 0.0625f;
        ew[8 + i] = bf2f((u16)v1[i]) * 0.0625f;
        eh[i]     = bf2f((u16)v2[i]) * 0.0625f;
        eh[8 + i] = bf2f((u16)v3[i]) * 0.0625f;
    }
#pragma unroll
    for (int i = 0; i < 8; ++i) ud[i] = bf2f((u16)v4[i]);
#pragma unroll
    for (int i = 0; i < 7; ++i) ud[8 + i] = bf2f((u16)v5[i]);

    float mw = ew[0], mh = eh[0];
#pragma unroll
    for (int i = 1; i < 16; ++i) { mw = fmaxf(mw, ew[i]); mh = fmaxf(mh, eh[i]); }
    float sw = 0.f, sh = 0.f;
#pragma unroll
    for (int i = 0; i < 16; ++i) {
        ew[i] = __expf(ew[i] - mw); sw += ew[i];
        eh[i] = __expf(eh[i] - mh); sh += eh[i];
    }
    const float kw = 20.f * (1.f - 1.6e-7f) / sw;
    const float kh = 20.f * (1.f - 1.6e-7f) / sh;

    float cwk = -10.f, chk = -10.f;
    float icw = -10.f, ich = -10.f, iw = 1.f, ih = 1.f, udl = 0.f, udr = 0.f;
    int selk = 0;
#pragma unroll
    for (int k = 0; k < 16; ++k) {
        const float cw1 = (k == 15) ? 10.f : cwk + (2e-7f + kw * ew[k]);
        const float ch1 = (k == 15) ? 10.f : chk + (2e-7f + kh * eh[k]);
        if (xs >= cwk) {
            selk = k;
            icw = cwk; iw = cw1 - cwk;
            ich = chk; ih = ch1 - chk;
            udl = (k >= 1)  ? ud[k - 1] : 0.f;
            udr = (k <= 14) ? ud[k]     : 0.f;
        }
        cwk = cw1; chk = ch1;
    }
    float d0 = (selk == 0)  ? 1.f : 1e-8f + splusf(udl);
    float d1 = (selk == 15) ? 1.f : 1e-8f + splusf(udr);
    float delta = ih / iw;
    float t = (xs - icw) / iw;
    float tt = t * (1.f - t);
    float denom = delta + (d0 + d1 - 2.f * delta) * tt;
    float y = ich + ih * (delta * t * t + d0 * tt) / denom;
    float omt = 1.f - t;
    float dnum = delta * delta * (d1 * t * t + 2.f * delta * tt + d0 * omt * omt);
    float ldv = __logf(dnum) - 2.f * __logf(denom);
    if (!inside) { y = xin; ldv = 0.f; }

    Xn[(size_t)b * 64 + fg] = y;
    XFnext[(size_t)b * 64 + (63 - fg)] = y;
    AXE[(size_t)b * 96 + (63 - fg)] = f2bf(y);

    float other = __shfl_xor(ldv, 1);
    if (fi == 0) {
        size_t o = (size_t)b * 32 + blockIdx.y;
        float v = ldv + other;
        LDP[o] = first ? v : (LDP[o] + v);
    }
}

// ---------------------------------------------------------------------------
// finals: stick-breaking + per-sample objective, then reduction
// ---------------------------------------------------------------------------
__global__ __launch_bounds__(256) void final1(
    const float* __restrict__ X, const float* __restrict__ z,
    const float* __restrict__ LDP, const float* __restrict__ DM,
    float* __restrict__ PART)
{
    int tid = threadIdx.x;
    int b = blockIdx.x * 256 + tid;
    float ldt = 0.f;
    for (int g = 0; g < 32; ++g) ldt += LDP[(size_t)b * 32 + g];
    float pre = 0.f, lvs = 0.f, wls = 0.f, lp = 0.f, tdm = 0.f, tsq = 0.f;
    const float LCLIP = -23.02585093f;
    for (int i = 0; i < 64; ++i) {
        float xi = X[(size_t)b * 64 + i];
        float lv = -splusf(-xi), l1 = -splusf(xi);
        float lt = lv + pre;
        float th = __expf(lt);
        lp += fmaxf(lt, LCLIP);
        tdm += th * DM[i]; tsq += th * th;
        lvs += lv; wls += (float)(64 - i) * l1;
        pre += l1;
    }
    float th = __expf(pre);
    lp += fmaxf(pre, LCLIP); tdm += th * DM[64]; tsq += th * th;
    float zs = 0.f;
    for (int i = 0; i < 64; ++i) { float zz = z[(size_t)b * 64 + i]; zs += zz * zz; }
    float logqz = -0.5f * zs - 58.812066f;
    float log_q = logqz - (ldt + lvs + wls);
    float log_lik = -0.5f * (DM[65] - 2.f * tdm + tsq);
    float val = log_q - lp - log_lik;

    __shared__ float red[256];
    red[tid] = val; __syncthreads();
    for (int s = 128; s > 0; s >>= 1) {
        if (tid < s) red[tid] += red[tid + s];
        __syncthreads();
    }
    if (tid == 0) PART[blockIdx.x] = red[0];
}

__global__ __launch_bounds__(64) void final2(const float* __restrict__ PART,
                                             float* __restrict__ out)
{
    int tid = threadIdx.x;
    float s = (tid < 32) ? PART[tid] : 0.f;
    for (int o = 16; o > 0; o >>= 1) s += __shfl_down(s, o);
    if (tid == 0) out[0] = s * (1.f / 8192.f);
}

// ---------------------------------------------------------------------------
extern "C" void kernel_launch(void* const* d_in, const int* in_sizes, int n_in,
                              void* d_out, int out_size, void* d_ws, size_t ws_size,
                              hipStream_t stream)
{
    (void)in_sizes; (void)n_in; (void)out_size; (void)ws_size;
    const float* z    = (const float*)d_in[0];
    const float* eta  = (const float*)d_in[1];
    const float* dat  = (const float*)d_in[2];
    const float* Win  = (const float*)d_in[3];
    const float* bin  = (const float*)d_in[4];
    const float* Wctx = (const float*)d_in[5];
    const float* bctx = (const float*)d_in[6];
    const float* Wblk = (const float*)d_in[7];
    const float* bblk = (const float*)d_in[8];
    const float* Wout = (const float*)d_in[9];
    const float* bout = (const float*)d_in[10];
    float* out = (float*)d_out;

    char* w = (char*)d_ws;
    size_t off = 0;
    auto alloc = [&](size_t bytes) {
        void* p = w + off;
        off += (bytes + 255) & ~(size_t)255;
        return p;
    };
    u16*   W1  = (u16*)  alloc(8L * 256 * 96 * 2);
    float* B1  = (float*)alloc(8L * 256 * 4);
    u16*   WB  = (u16*)  alloc(8L * 4 * 256 * 256 * 2);
    u16*   WO  = (u16*)  alloc(8L * 3072 * 256 * 2);
    float* BO  = (float*)alloc(8L * 3072 * 4);
    u16*   AXE = (u16*)  alloc(8192L * 96 * 2);
    float* XFa = (float*)alloc(8192L * 64 * 4);
    float* XFb = (float*)alloc(8192L * 64 * 4);
    float* XC  = (float*)alloc(8192L * 64 * 4);
    u16*   HB  = (u16*)  alloc(8192L * 256 * 2);
    float* LDP = (float*)alloc(8192L * 32 * 4);
    float* DM  = (float*)alloc(66 * 4);
    float* PART= (float*)alloc(64 * 4);

    setup_w<<<dim3(2048), dim3(256), 0, stream>>>(
        Win, bin, Wctx, bctx, Wblk, Wout, bout, eta, W1, B1, WB, WO, BO, AXE);
    dstat<<<dim3(1), dim3(128), 0, stream>>>(dat, DM);
    prep0<<<dim3(2048), dim3(256), 0, stream>>>(z, XFa, AXE);

    for (int l = 0; l < 8; ++l) {
        float* XFin  = (l & 1) ? XFb : XFa;
        float* XFout = (l & 1) ? XFa : XFb;
        fused_mid<<<dim3(512), dim3(512), 0, stream>>>(
            AXE, W1 + (size_t)l * 24576, B1 + l * 256,
            WB + (size_t)l * 262144, bblk + (size_t)l * 4 * 256, HB);
        gemm_out_spline<<<dim3(64, 32), dim3(256), 0, stream>>>(
            HB, WO + (size_t)l * 786432, BO + l * 3072, XFin,
            XC, XFout, AXE, LDP, (l == 0) ? 1 : 0);
    }
    final1<<<dim3(32), dim3(256), 0, stream>>>(XC, z, LDP, DM, PART);
    final2<<<dim3(1), dim3(64), 0, stream>>>(PART, out);
}

// Round 12
// 359.592 us; speedup vs baseline: 1.9033x; 1.1412x over previous
//
#include <hip/hip_runtime.h>
#include <math.h>

typedef float f32x4 __attribute__((ext_vector_type(4)));
typedef short bf16x8 __attribute__((ext_vector_type(8)));
typedef unsigned short u16;

typedef const __attribute__((address_space(1))) unsigned int ga_u32;
typedef __attribute__((address_space(3))) unsigned int ls_u32;

__device__ __forceinline__ void gl16(const void* g, void* l) {
    __builtin_amdgcn_global_load_lds((ga_u32*)g, (ls_u32*)l, 16, 0, 0);
}

__device__ __forceinline__ u16 f2bf(float f) {
    union { float f; unsigned u; } v; v.f = f;
    return (u16)((v.u + 0x7FFFu + ((v.u >> 16) & 1u)) >> 16);
}
__device__ __forceinline__ float bf2f(u16 h) {
    union { unsigned u; float f; } v; v.u = ((unsigned)h) << 16;
    return v.f;
}
__device__ __forceinline__ float splusf(float x) {
    return fmaxf(x, 0.f) + __logf(1.f + __expf(-fabsf(x)));
}

#define MID_ACT_P 264

// ---------------------------------------------------------------------------
// setup: masked bf16 weights.
// W1/WB: per (layer, stage, wave) REGISTER-FRAGMENT layout [frag][lane][8]
//   (wave-exclusive 32 channels; frag = ks*2+f; element e of frag for lane:
//    row = w*32 + f*16 + (lane&15), col = ks*32 + (lane>>4)*8 + e)
//   -> each wave loads NF coalesced dwordx4 (1KB each), zero LDS, zero barriers.
// WO: chunk-major slice tiles (R11-proven, gl16 linear staging).
// ---------------------------------------------------------------------------
__global__ __launch_bounds__(256) void setup_w(
    const float* __restrict__ Win, const float* __restrict__ bin,
    const float* __restrict__ Wctx, const float* __restrict__ bctx,
    const float* __restrict__ Wblk, const float* __restrict__ Wout,
    const float* __restrict__ bout, const float* __restrict__ eta,
    u16* __restrict__ W1, float* __restrict__ B1, u16* __restrict__ WB,
    u16* __restrict__ WO, float* __restrict__ BO, u16* __restrict__ AXE)
{
    const long N1 = 8L * 8 * 8 * 64 * 8;         // W1: [l][w][frag8(6used)][lane][8]
    const long N2 = 8L * 256;
    const long N3 = 8L * 4 * 8 * 16 * 64 * 8;    // WB: [l][bi][w][frag16][lane][8]
    const long N4 = 8L * 32 * 8 * 4 * 96 * 8;    // WO: [l][y32][ks8][chunk4][row96][8]
    const long N5 = 8L * 3072;
    const long N6 = 8192L * 32;
    const long tot = N1 + N2 + N3 + N4 + N5 + N6;
    for (long i = (long)blockIdx.x * blockDim.x + threadIdx.x; i < tot;
         i += (long)gridDim.x * blockDim.x) {
        long t = i;
        if (t < N1) {
            int off = (int)(t & 7), lane = (int)((t >> 3) & 63);
            int frag = (int)((t >> 9) & 7), wv = (int)((t >> 12) & 7);
            long l = t >> 15;
            int ks = frag >> 1, f = frag & 1;
            int row = wv * 32 + f * 16 + (lane & 15);
            int c = ks * 32 + ((lane >> 4) << 3) + off;
            float v = 0.f;
            if (c < 64)      v = Win[(l * 256 + row) * 64 + c] * (((row % 63) >= c) ? 1.f : 0.f);
            else if (c < 96) v = Wctx[(l * 256 + row) * 32 + (c - 64)];
            W1[t] = f2bf(v);
        } else if ((t -= N1) < N2) {
            B1[t] = bin[t] + bctx[t];
        } else if ((t -= N2) < N3) {
            int off = (int)(t & 7), lane = (int)((t >> 3) & 63);
            int frag = (int)((t >> 9) & 15), wv = (int)((t >> 13) & 7);
            int bi = (int)((t >> 16) & 3);
            long l = t >> 18;
            int row = wv * 32 + (frag & 1) * 16 + (lane & 15);
            int c = ((frag >> 1) << 5) + ((lane >> 4) << 3) + off;
            float v = Wblk[(((size_t)l * 4 + bi) * 256 + row) * 256 + c] *
                      (((row % 63) >= (c % 63)) ? 1.f : 0.f);
            WB[t] = f2bf(v);
        } else if ((t -= N3) < N4) {
            long l = t / 786432; int rem = (int)(t % 786432);
            int y = rem / 24576, r2 = rem % 24576;
            int ks = r2 / 3072, r3 = r2 % 3072;
            int chunk = r3 / 768, r4 = r3 % 768;
            int row = r4 / 8, off = r4 % 8;
            int op = y * 96 + row;
            int j = ks * 32 + chunk * 8 + off;
            int fd = op / 48, mm = op % 48;
            float v = 0.f;
            if (mm < 47 && fd > (j % 63))
                v = Wout[((size_t)l * 3008 + fd * 47 + mm) * 256 + j];
            WO[t] = f2bf(v);
        } else if ((t -= N4) < N5) {
            long l = t / 3072; int op = (int)(t % 3072);
            int fd = op / 48, mm = op % 48;
            BO[t] = (mm < 47) ? bout[l * 3008 + (long)fd * 47 + mm] : 0.f;
        } else {
            t -= N5;
            long b = t / 32; int p = (int)(t % 32);
            AXE[b * 96 + 64 + p] = f2bf(eta[t]);
        }
    }
}

// ---------------------------------------------------------------------------
// data stats
// ---------------------------------------------------------------------------
__global__ __launch_bounds__(128) void dstat(const float* __restrict__ D,
                                             float* __restrict__ DM)
{
    int j = threadIdx.x;
    float s = 0.f, q = 0.f;
    if (j < 65) {
        for (int m = 0; m < 256; ++m) {
            float v = D[m * 65 + j];
            s += v; q += v * v;
        }
        DM[j] = s * (1.f / 256.f);
    }
    __shared__ float red[128];
    red[j] = q; __syncthreads();
    for (int st = 64; st > 0; st >>= 1) {
        if (j < st) red[j] += red[j + st];
        __syncthreads();
    }
    if (j == 0) DM[65] = red[0] * (1.f / 256.f);
}

// ---------------------------------------------------------------------------
// prep0: flip z -> XF (f32) + AXE cols 0..63 (bf16)
// ---------------------------------------------------------------------------
__global__ __launch_bounds__(256) void prep0(
    const float* __restrict__ z, float* __restrict__ XF, u16* __restrict__ AXE)
{
    size_t gt = (size_t)blockIdx.x * 256 + threadIdx.x;
    size_t b = gt >> 6; int f = (int)(gt & 63);
    float v = z[b * 64 + (63 - f)];
    XF[gt] = v;
    AXE[b * 96 + f] = f2bf(v);
}

// ---------------------------------------------------------------------------
// mid stage, register-weight version: wave-exclusive weights loaded via NF
// coalesced dwordx4 straight to VGPRs (pre-tiled [frag][lane][8] layout).
// NO LDS weight traffic, NO barriers inside the stage.
// ---------------------------------------------------------------------------
template<int NF>
__device__ __forceinline__ void mid_stage_reg(
    const u16* __restrict__ gW, const u16* __restrict__ act,
    int lane, int fr, int kg, f32x4 (&T)[2])
{
    bf16x8 wf[NF];
#pragma unroll
    for (int j = 0; j < NF; ++j)
        wf[j] = *(const bf16x8*)(gW + (j * 64 + lane) * 8);
#pragma unroll
    for (int ks = 0; ks < NF / 2; ++ks) {
        bf16x8 af = *(const bf16x8*)&act[fr * MID_ACT_P + ks * 32 + kg * 8];
        T[0] = __builtin_amdgcn_mfma_f32_16x16x32_bf16(wf[ks * 2 + 0], af, T[0], 0, 0, 0);
        T[1] = __builtin_amdgcn_mfma_f32_16x16x32_bf16(wf[ks * 2 + 1], af, T[1], 0, 0, 0);
    }
}

// fused_mid: all 5 mid GEMMs. 512 blocks x 16 batch rows, 512 thr
// (8 waves x 32 wave-exclusive channels). LDS = act only (8.4 KB).
// 2 barriers per stage boundary (act rewrite), none inside stages.
// Final epilogue writes HB in the out-kernel's tiled layout.
__global__ __launch_bounds__(512) void fused_mid(
    const u16* __restrict__ AXE, const u16* __restrict__ W1l,
    const float* __restrict__ B1l, const u16* __restrict__ WBl,
    const float* __restrict__ bbl, u16* __restrict__ HB)
{
    __shared__ u16 act[16 * MID_ACT_P];   // 8448 B
    const int tid = threadIdx.x;
    const int lane = tid & 63;
    const int wv = tid >> 6;
    const int fr = lane & 15, kg = lane >> 4;
    const int b0 = blockIdx.x * 16;
    const int ch0 = wv * 32;

    if (tid < 192) {
        int row = tid / 12, part = tid - row * 12;
        *(int4*)&act[row * MID_ACT_P + part * 8] =
            *(const int4*)&AXE[(size_t)(b0 + row) * 96 + part * 8];
    }

    f32x4 H[2], T[2];

    auto zeroT = [&]() {
        T[0] = (f32x4){0.f, 0.f, 0.f, 0.f};
        T[1] = (f32x4){0.f, 0.f, 0.f, 0.f};
    };
    // mode 0: H=T+b, act=relu(H); 1: act=relu(T+b); 2: H+=T+b, act=relu(H);
    // mode 3: H+=T+b, HB=bf16(H) global (tiled layout)
    auto epi = [&](const float* bias, int mode) {
#pragma unroll
        for (int m = 0; m < 2; ++m) {
            const int cb = ch0 + m * 16 + kg * 4;
            const float4 bs = *(const float4*)&bias[cb];
            f32x4 v = T[m];
            v[0] += bs.x; v[1] += bs.y; v[2] += bs.z; v[3] += bs.w;
            if (mode == 0) H[m] = v;
            if (mode == 2 || mode == 3) {
                H[m][0] += v[0]; H[m][1] += v[1];
                H[m][2] += v[2]; H[m][3] += v[3];
                v = H[m];
            }
            short4 q;
            if (mode != 3) {
                q.x = (short)f2bf(fmaxf(v[0], 0.f));
                q.y = (short)f2bf(fmaxf(v[1], 0.f));
                q.z = (short)f2bf(fmaxf(v[2], 0.f));
                q.w = (short)f2bf(fmaxf(v[3], 0.f));
                *(short4*)&act[fr * MID_ACT_P + cb] = q;
            } else {
                q.x = (short)f2bf(v[0]); q.y = (short)f2bf(v[1]);
                q.z = (short)f2bf(v[2]); q.w = (short)f2bf(v[3]);
                const int b = b0 + fr;
                const size_t idx =
                    (((size_t)(b >> 7) * 8 + (cb >> 5)) * 4 + ((cb >> 3) & 3)) * 1024
                    + (size_t)(b & 127) * 8 + (cb & 7);
                *(short4*)&HB[idx] = q;
            }
        }
    };

    zeroT();
    __syncthreads();                       // act staged
    mid_stage_reg<6>(W1l + wv * 4096, act, lane, fr, kg, T);
    __syncthreads();                       // act reads done
    epi(B1l, 0);
    zeroT();
    __syncthreads();                       // act writes visible
    mid_stage_reg<16>(WBl + 0 * 65536 + wv * 8192, act, lane, fr, kg, T);
    __syncthreads();
    epi(bbl, 1);
    zeroT();
    __syncthreads();
    mid_stage_reg<16>(WBl + 1 * 65536 + wv * 8192, act, lane, fr, kg, T);
    __syncthreads();
    epi(bbl + 256, 2);
    zeroT();
    __syncthreads();
    mid_stage_reg<16>(WBl + 2 * 65536 + wv * 8192, act, lane, fr, kg, T);
    __syncthreads();
    epi(bbl + 2 * 256, 1);
    zeroT();
    __syncthreads();
    mid_stage_reg<16>(WBl + 3 * 65536 + wv * 8192, act, lane, fr, kg, T);
    __syncthreads();
    epi(bbl + 3 * 256, 3);
}

// ---------------------------------------------------------------------------
// Out-GEMM (128x96 tile, K=256) + fused RQS spline (R11-proven, unchanged).
// ---------------------------------------------------------------------------
__global__ __launch_bounds__(256) void gemm_out_spline(
    const u16* __restrict__ A, const u16* __restrict__ Wo,
    const float* __restrict__ bo, const float* __restrict__ XF,
    float* __restrict__ Xn, float* __restrict__ XFnext, u16* __restrict__ AXE,
    float* __restrict__ LDP, int first)
{
    __shared__ u16 SM[14336];      // A dbuf 2x4096 | B dbuf 2x3072 (28672 B)
    const int tid = threadIdx.x;
    const int lane = tid & 63, wv = tid >> 6;
    const int wm = wv >> 1, wn = wv & 1;
    const int fr = lane & 15, kg = lane >> 4;
    const int m0 = blockIdx.x * 128, n0 = blockIdx.y * 96;

    u16* Ab = SM;
    u16* Bb = SM + 8192;

    const u16* gAblk = A  + (size_t)blockIdx.x * 32768;
    const u16* gBblk = Wo + (size_t)blockIdx.y * 24576;

    f32x4 acc[4][3];
#pragma unroll
    for (int m = 0; m < 4; ++m)
#pragma unroll
        for (int n = 0; n < 3; ++n) acc[m][n] = (f32x4){0.f, 0.f, 0.f, 0.f};

    gl16(gAblk + tid * 8,         Ab + tid * 8);
    gl16(gAblk + (256 + tid) * 8, Ab + (256 + tid) * 8);
    gl16(gBblk + tid * 8,         Bb + tid * 8);
    if (tid < 128)
        gl16(gBblk + (256 + tid) * 8, Bb + (256 + tid) * 8);

#pragma unroll
    for (int ks = 0; ks < 8; ++ks) {
        __syncthreads();
        if (ks < 7) {
            const u16* sa = gAblk + (ks + 1) * 4096;
            const u16* sb = gBblk + (ks + 1) * 3072;
            u16* na = Ab + ((ks + 1) & 1) * 4096;
            u16* nb = Bb + ((ks + 1) & 1) * 3072;
            gl16(sa + tid * 8,         na + tid * 8);
            gl16(sa + (256 + tid) * 8, na + (256 + tid) * 8);
            gl16(sb + tid * 8,         nb + tid * 8);
            if (tid < 128)
                gl16(sb + (256 + tid) * 8, nb + (256 + tid) * 8);
        }
        const u16* cA = Ab + (ks & 1) * 4096;
        const u16* cB = Bb + (ks & 1) * 3072;
        bf16x8 af[4], bf[3];
#pragma unroll
        for (int m = 0; m < 4; ++m)
            af[m] = *(const bf16x8*)&cA[kg * 1024 + (wm * 64 + m * 16 + fr) * 8];
#pragma unroll
        for (int n = 0; n < 3; ++n)
            bf[n] = *(const bf16x8*)&cB[kg * 768 + (wn * 48 + n * 16 + fr) * 8];
#pragma unroll
        for (int m = 0; m < 4; ++m)
#pragma unroll
            for (int n = 0; n < 3; ++n)
                acc[m][n] = __builtin_amdgcn_mfma_f32_16x16x32_bf16(bf[n], af[m], acc[m][n], 0, 0, 0);
    }
    __syncthreads();

#pragma unroll
    for (int m = 0; m < 4; ++m) {
        const int row = wm * 64 + m * 16 + fr;
#pragma unroll
        for (int n = 0; n < 3; ++n) {
            const int c0 = wn * 48 + n * 16 + kg * 4;
            const float4 bs = *(const float4*)&bo[n0 + c0];
            short4 q;
            q.x = (short)f2bf(acc[m][n][0] + bs.x);
            q.y = (short)f2bf(acc[m][n][1] + bs.y);
            q.z = (short)f2bf(acc[m][n][2] + bs.z);
            q.w = (short)f2bf(acc[m][n][3] + bs.w);
            *(short4*)&SM[row * 104 + c0] = q;
        }
    }
    __syncthreads();

    const int r = tid >> 1, fi = tid & 1;
    const int b = m0 + r;
    const int fg = blockIdx.y * 2 + fi;
    const u16* o_ = &SM[r * 104 + fi * 48];
    bf16x8 v0 = *(const bf16x8*)(o_);
    bf16x8 v1 = *(const bf16x8*)(o_ + 8);
    bf16x8 v2 = *(const bf16x8*)(o_ + 16);
    bf16x8 v3 = *(const bf16x8*)(o_ + 24);
    bf16x8 v4 = *(const bf16x8*)(o_ + 32);
    bf16x8 v5 = *(const bf16x8*)(o_ + 40);

    float xin = XF[(size_t)b * 64 + fg];
    bool inside = (xin >= -10.f) && (xin <= 10.f);
    float xs = fminf(fmaxf(xin, -10.f), 10.f);

    float ew[16], eh[16], ud[15];
#pragma unroll
    for (int i = 0; i < 8; ++i) {
        ew[i]     = bf2f((u16)v0[i]) * 0.0625f;
        ew[8 + i] = bf2f((u16)v1[i]) * 0.0625f;
        eh[i]     = bf2f((u16)v2[i]) * 0.0625f;
        eh[8 + i] = bf2f((u16)v3[i]) * 0.0625f;
    }
#pragma unroll
    for (int i = 0; i < 8; ++i) ud[i] = bf2f((u16)v4[i]);
#pragma unroll
    for (int i = 0; i < 7; ++i) ud[8 + i] = bf2f((u16)v5[i]);

    float mw = ew[0], mh = eh[0];
#pragma unroll
    for (int i = 1; i < 16; ++i) { mw = fmaxf(mw, ew[i]); mh = fmaxf(mh, eh[i]); }
    float sw = 0.f, sh = 0.f;
#pragma unroll
    for (int i = 0; i < 16; ++i) {
        ew[i] = __expf(ew[i] - mw); sw += ew[i];
        eh[i] = __expf(eh[i] - mh); sh += eh[i];
    }
    const float kw = 20.f * (1.f - 1.6e-7f) / sw;
    const float kh = 20.f * (1.f - 1.6e-7f) / sh;

    float cwk = -10.f, chk = -10.f;
    float icw = -10.f, ich = -10.f, iw = 1.f, ih = 1.f, udl = 0.f, udr = 0.f;
    int selk = 0;
#pragma unroll
    for (int k = 0; k < 16; ++k) {
        const float cw1 = (k == 15) ? 10.f : cwk + (2e-7f + kw * ew[k]);
        const float ch1 = (k == 15) ? 10.f : chk + (2e-7f + kh * eh[k]);
        if (xs >= cwk) {
            selk = k;
            icw = cwk; iw = cw1 - cwk;
            ich = chk; ih = ch1 - chk;
            udl = (k >= 1)  ? ud[k - 1] : 0.f;
            udr = (k <= 14) ? ud[k]     : 0.f;
        }
        cwk = cw1; chk = ch1;
    }
    float d0 = (selk == 0)  ? 1.f : 1e-8f + splusf(udl);
    float d1 = (selk == 15) ? 1.f : 1e-8f + splusf(udr);
    float delta = ih / iw;
    float t = (xs - icw) / iw;
    float tt = t * (1.f - t);
    float denom = delta + (d0 + d1 - 2.f * delta) * tt;
    float y = ich + ih * (delta * t * t + d0 * tt) / denom;
    float omt = 1.f - t;
    float dnum = delta * delta * (d1 * t * t + 2.f * delta * tt + d0 * omt * omt);
    float ldv = __logf(dnum) - 2.f * __logf(denom);
    if (!inside) { y = xin; ldv = 0.f; }

    Xn[(size_t)b * 64 + fg] = y;
    XFnext[(size_t)b * 64 + (63 - fg)] = y;
    AXE[(size_t)b * 96 + (63 - fg)] = f2bf(y);

    float other = __shfl_xor(ldv, 1);
    if (fi == 0) {
        size_t o = (size_t)b * 32 + blockIdx.y;
        float v = ldv + other;
        LDP[o] = first ? v : (LDP[o] + v);
    }
}

// ---------------------------------------------------------------------------
// finals: stick-breaking + per-sample objective, then reduction
// ---------------------------------------------------------------------------
__global__ __launch_bounds__(256) void final1(
    const float* __restrict__ X, const float* __restrict__ z,
    const float* __restrict__ LDP, const float* __restrict__ DM,
    float* __restrict__ PART)
{
    int tid = threadIdx.x;
    int b = blockIdx.x * 256 + tid;
    float ldt = 0.f;
    for (int g = 0; g < 32; ++g) ldt += LDP[(size_t)b * 32 + g];
    float pre = 0.f, lvs = 0.f, wls = 0.f, lp = 0.f, tdm = 0.f, tsq = 0.f;
    const float LCLIP = -23.02585093f;
    for (int i = 0; i < 64; ++i) {
        float xi = X[(size_t)b * 64 + i];
        float lv = -splusf(-xi), l1 = -splusf(xi);
        float lt = lv + pre;
        float th = __expf(lt);
        lp += fmaxf(lt, LCLIP);
        tdm += th * DM[i]; tsq += th * th;
        lvs += lv; wls += (float)(64 - i) * l1;
        pre += l1;
    }
    float th = __expf(pre);
    lp += fmaxf(pre, LCLIP); tdm += th * DM[64]; tsq += th * th;
    float zs = 0.f;
    for (int i = 0; i < 64; ++i) { float zz = z[(size_t)b * 64 + i]; zs += zz * zz; }
    float logqz = -0.5f * zs - 58.812066f;
    float log_q = logqz - (ldt + lvs + wls);
    float log_lik = -0.5f * (DM[65] - 2.f * tdm + tsq);
    float val = log_q - lp - log_lik;

    __shared__ float red[256];
    red[tid] = val; __syncthreads();
    for (int s = 128; s > 0; s >>= 1) {
        if (tid < s) red[tid] += red[tid + s];
        __syncthreads();
    }
    if (tid == 0) PART[blockIdx.x] = red[0];
}

__global__ __launch_bounds__(64) void final2(const float* __restrict__ PART,
                                             float* __restrict__ out)
{
    int tid = threadIdx.x;
    float s = (tid < 32) ? PART[tid] : 0.f;
    for (int o = 16; o > 0; o >>= 1) s += __shfl_down(s, o);
    if (tid == 0) out[0] = s * (1.f / 8192.f);
}

// ---------------------------------------------------------------------------
extern "C" void kernel_launch(void* const* d_in, const int* in_sizes, int n_in,
                              void* d_out, int out_size, void* d_ws, size_t ws_size,
                              hipStream_t stream)
{
    (void)in_sizes; (void)n_in; (void)out_size; (void)ws_size;
    const float* z    = (const float*)d_in[0];
    const float* eta  = (const float*)d_in[1];
    const float* dat  = (const float*)d_in[2];
    const float* Win  = (const float*)d_in[3];
    const float* bin  = (const float*)d_in[4];
    const float* Wctx = (const float*)d_in[5];
    const float* bctx = (const float*)d_in[6];
    const float* Wblk = (const float*)d_in[7];
    const float* bblk = (const float*)d_in[8];
    const float* Wout = (const float*)d_in[9];
    const float* bout = (const float*)d_in[10];
    float* out = (float*)d_out;

    char* w = (char*)d_ws;
    size_t off = 0;
    auto alloc = [&](size_t bytes) {
        void* p = w + off;
        off += (bytes + 255) & ~(size_t)255;
        return p;
    };
    u16*   W1  = (u16*)  alloc(8L * 32768 * 2);          // padded reg-frag layout
    float* B1  = (float*)alloc(8L * 256 * 4);
    u16*   WB  = (u16*)  alloc(8L * 4 * 65536 * 2);      // reg-frag layout
    u16*   WO  = (u16*)  alloc(8L * 786432 * 2);         // chunk-major tiles
    float* BO  = (float*)alloc(8L * 3072 * 4);
    u16*   AXE = (u16*)  alloc(8192L * 96 * 2);
    float* XFa = (float*)alloc(8192L * 64 * 4);
    float* XFb = (float*)alloc(8192L * 64 * 4);
    float* XC  = (float*)alloc(8192L * 64 * 4);
    u16*   HB  = (u16*)  alloc(8192L * 256 * 2);
    float* LDP = (float*)alloc(8192L * 32 * 4);
    float* DM  = (float*)alloc(66 * 4);
    float* PART= (float*)alloc(64 * 4);

    setup_w<<<dim3(2048), dim3(256), 0, stream>>>(
        Win, bin, Wctx, bctx, Wblk, Wout, bout, eta, W1, B1, WB, WO, BO, AXE);
    dstat<<<dim3(1), dim3(128), 0, stream>>>(dat, DM);
    prep0<<<dim3(2048), dim3(256), 0, stream>>>(z, XFa, AXE);

    for (int l = 0; l < 8; ++l) {
        float* XFin  = (l & 1) ? XFb : XFa;
        float* XFout = (l & 1) ? XFa : XFb;
        fused_mid<<<dim3(512), dim3(512), 0, stream>>>(
            AXE, W1 + (size_t)l * 32768, B1 + l * 256,
            WB + (size_t)l * 262144, bblk + (size_t)l * 4 * 256, HB);
        gemm_out_spline<<<dim3(64, 32), dim3(256), 0, stream>>>(
            HB, WO + (size_t)l * 786432, BO + l * 3072, XFin,
            XC, XFout, AXE, LDP, (l == 0) ? 1 : 0);
    }
    final1<<<dim3(32), dim3(256), 0, stream>>>(XC, z, LDP, DM, PART);
    final2<<<dim3(1), dim3(64), 0, stream>>>(PART, out);
}